// Round 2
// baseline (334.758 us; speedup 1.0000x reference)
//
#include <hip/hip_runtime.h>

// SoftFaceColorShader: pytorch3d-style softmax blending.
// Shapes: pix_to_face [N,H,W,K] int, bary [N,H,W,K,3] f32, zbuf/dists [N,H,W,K] f32,
// face_colors [N,F,D] f32. Output [N,H,W,D+1] f32 (D=3 -> float4 per pixel).
//
// Memory-bound: ~302 MB streamed once; face_colors (1.92 MB) stays L2-resident.

#define KN 8
#define KH 384
#define KW 384
#define KK 10
#define KF 20000
#define KD 3

__global__ __launch_bounds__(256) void soft_face_shader_kernel(
    const int*   __restrict__ p2f,    // [P, K]
    const float* __restrict__ bary,   // [P, K, 3]
    const float* __restrict__ zbuf,   // [P, K]
    const float* __restrict__ dists,  // [P, K]
    const float* __restrict__ fcol,   // [N*F, 3]
    float*       __restrict__ out,    // [P, 4]
    int P)
{
    const float SIGMA = 1e-4f;
    const float GAMMA = 1e-2f;
    const float ZNEAR = 1.0f, ZFAR = 100.0f;
    const float EPS = 1e-10f;

    int pix = blockIdx.x * blockDim.x + threadIdx.x;
    if (pix >= P) return;

    // ---- vectorized per-pixel loads (all 8B-aligned: 40B / 120B strides) ----
    int face[KK];
    {
        const int2* p = reinterpret_cast<const int2*>(p2f + (size_t)pix * KK);
        #pragma unroll
        for (int i = 0; i < KK / 2; ++i) { int2 v = p[i]; face[2*i] = v.x; face[2*i+1] = v.y; }
    }
    float b[KK * 3];
    {
        const float2* p = reinterpret_cast<const float2*>(bary + (size_t)pix * KK * 3);
        #pragma unroll
        for (int i = 0; i < KK * 3 / 2; ++i) { float2 v = p[i]; b[2*i] = v.x; b[2*i+1] = v.y; }
    }
    float z[KK], dist[KK];
    {
        const float2* p = reinterpret_cast<const float2*>(zbuf + (size_t)pix * KK);
        #pragma unroll
        for (int i = 0; i < KK / 2; ++i) { float2 v = p[i]; z[2*i] = v.x; z[2*i+1] = v.y; }
    }
    {
        const float2* p = reinterpret_cast<const float2*>(dists + (size_t)pix * KK);
        #pragma unroll
        for (int i = 0; i < KK / 2; ++i) { float2 v = p[i]; dist[2*i] = v.x; dist[2*i+1] = v.y; }
    }

    // ---- pass 1: prob, z_inv, running max / alpha ----
    float prob[KK], zinv[KK];
    float one_minus = 1.0f;
    float zmax = EPS;
    #pragma unroll
    for (int k = 0; k < KK; ++k) {
        bool m = face[k] >= 0;
        // sigmoid(-d/sigma) = 1/(1+exp(d/sigma))
        float t  = dist[k] / SIGMA;
        float pr = m ? 1.0f / (1.0f + __expf(t)) : 0.0f;
        prob[k] = pr;
        one_minus *= (1.0f - pr);
        float zi = m ? (ZFAR - z[k]) / (ZFAR - ZNEAR) : 0.0f;
        zinv[k] = zi;
        zmax = fmaxf(zmax, zi);
    }
    float alpha = 1.0f - one_minus;

    // ---- pass 2: softmax weights, gather colors (L2-resident), accumulate ----
    float delta = fmaxf(__expf((EPS - zmax) / GAMMA), EPS);
    float denom = delta;
    float acc0 = 0.0f, acc1 = 0.0f, acc2 = 0.0f;
    #pragma unroll
    for (int k = 0; k < KK; ++k) {
        float w = prob[k] * __expf((zinv[k] - zmax) / GAMMA);
        denom += w;
        if (face[k] >= 0) {
            const float* c = fcol + (size_t)face[k] * 3;
            float bs = b[3*k] + b[3*k+1] + b[3*k+2];
            float wb = w * bs;
            acc0 = fmaf(wb, c[0], acc0);
            acc1 = fmaf(wb, c[1], acc1);
            acc2 = fmaf(wb, c[2], acc2);
        }
    }
    float inv = 1.0f / denom;
    float4 o = make_float4(acc0 * inv, acc1 * inv, acc2 * inv, alpha);
    reinterpret_cast<float4*>(out)[pix] = o;
}

extern "C" void kernel_launch(void* const* d_in, const int* in_sizes, int n_in,
                              void* d_out, int out_size, void* d_ws, size_t ws_size,
                              hipStream_t stream) {
    const int*   p2f   = (const int*)  d_in[0];
    const float* bary  = (const float*)d_in[1];
    const float* zbuf  = (const float*)d_in[2];
    const float* dists = (const float*)d_in[3];
    const float* fcol  = (const float*)d_in[4];
    float* out = (float*)d_out;

    const int P = KN * KH * KW;  // 1,179,648 pixels
    const int block = 256;
    const int grid = (P + block - 1) / block;  // 4608 blocks
    soft_face_shader_kernel<<<grid, block, 0, stream>>>(p2f, bary, zbuf, dists, fcol, out, P);
}